// Round 10
// baseline (223.559 us; speedup 1.0000x reference)
//
#include <hip/hip_runtime.h>
#include <math.h>

#define TT 2048
#define NH 16
#define HD 64
#define NB 32
#define HIDDEN 1024

typedef short s8v __attribute__((ext_vector_type(8)));
typedef float f4v __attribute__((ext_vector_type(4)));

// ---------------- bf16 helpers (header-independent, RNE) ----------------
__device__ __forceinline__ unsigned short f2bf(float x){
  unsigned u = __float_as_uint(x);
  unsigned r = (u + 0x7fffu + ((u>>16)&1u)) >> 16;
  return (unsigned short)r;
}
__device__ __forceinline__ float bf2f(unsigned short b){
  return __uint_as_float(((unsigned)b)<<16);
}
__device__ __forceinline__ void bsplit(float x, unsigned short& h, unsigned short& l){
  h = f2bf(x);
  l = f2bf(x - bf2f(h));
}

// ---------------- wave reductions ----------------
__device__ __forceinline__ float rmax32(float v){
#pragma unroll
  for(int o=16;o>0;o>>=1) v = fmaxf(v, __shfl_xor(v,o,32));
  return v;
}
__device__ __forceinline__ float rsum32(float v){
#pragma unroll
  for(int o=16;o>0;o>>=1) v += __shfl_xor(v,o,32);
  return v;
}

// ---------------- fused prep: split hs + transpose/split W* + Wc + gate + zero avgk ----------------
__global__ __launch_bounds__(256) void prep_all(
    const float* __restrict__ hs,
    const float* __restrict__ Wq, const float* __restrict__ Wk,
    const float* __restrict__ Wv, const float* __restrict__ Wo,
    const float* __restrict__ Wc,
    const float* __restrict__ Wg, const float* __restrict__ bg,
    unsigned short* __restrict__ hh, unsigned short* __restrict__ hl,
    unsigned short* __restrict__ wth, unsigned short* __restrict__ wtl,
    unsigned short* __restrict__ woth,
    unsigned short* __restrict__ wcth, unsigned short* __restrict__ wctl,
    float* __restrict__ gatep, float* __restrict__ out_avgk)
{
  __shared__ float SL[64*68];
  int bx = blockIdx.x;
  int t = threadIdx.x;
  if(bx==0 && t==0) out_avgk[0] = 0.f;
  if(bx < 2048){
    int i = (bx*256 + t)*4;
    float4 x = *(const float4*)(hs + i);
    ushort4 hv, lv;
    bsplit(x.x, hv.x, lv.x); bsplit(x.y, hv.y, lv.y);
    bsplit(x.z, hv.z, lv.z); bsplit(x.w, hv.w, lv.w);
    *(ushort4*)(hh + i) = hv;
    *(ushort4*)(hl + i) = lv;
    return;
  }
  if(bx < 3072){
    float (*L)[68] = (float(*)[68])SL;
    int idx = bx - 2048;
    int z = idx>>8, ky = (idx>>4)&15, nx = idx&15;
    const float* W = (z==0)?Wq:((z==1)?Wk:((z==2)?Wv:Wo));
    int k0 = ky*64, n0 = nx*64;
    int rr = t>>2, cg = t&3;
    const float* src = W + (size_t)(k0+rr)*1024 + n0 + cg*16;
    float4 a = *(const float4*)(src);
    float4 b = *(const float4*)(src+4);
    float4 c = *(const float4*)(src+8);
    float4 d = *(const float4*)(src+12);
    *(float4*)&L[rr][cg*16+0]  = a;
    *(float4*)&L[rr][cg*16+4]  = b;
    *(float4*)&L[rr][cg*16+8]  = c;
    *(float4*)&L[rr][cg*16+12] = d;
    __syncthreads();
    int nr = t>>2, kg = t&3;
    unsigned short hb[16], lb[16];
#pragma unroll
    for(int j=0;j<16;j++){
      float v = L[kg*16+j][nr];
      bsplit(v, hb[j], lb[j]);
    }
    if(z<3){
      size_t orow = ((size_t)z*1024 + n0 + nr)*1024 + k0 + kg*16;
      *(ushort4*)(wth+orow+0)  = make_ushort4(hb[0],hb[1],hb[2],hb[3]);
      *(ushort4*)(wth+orow+4)  = make_ushort4(hb[4],hb[5],hb[6],hb[7]);
      *(ushort4*)(wth+orow+8)  = make_ushort4(hb[8],hb[9],hb[10],hb[11]);
      *(ushort4*)(wth+orow+12) = make_ushort4(hb[12],hb[13],hb[14],hb[15]);
      *(ushort4*)(wtl+orow+0)  = make_ushort4(lb[0],lb[1],lb[2],lb[3]);
      *(ushort4*)(wtl+orow+4)  = make_ushort4(lb[4],lb[5],lb[6],lb[7]);
      *(ushort4*)(wtl+orow+8)  = make_ushort4(lb[8],lb[9],lb[10],lb[11]);
      *(ushort4*)(wtl+orow+12) = make_ushort4(lb[12],lb[13],lb[14],lb[15]);
    }else{
      size_t orow = ((size_t)n0 + nr)*1024 + k0 + kg*16;
      *(ushort4*)(woth+orow+0)  = make_ushort4(hb[0],hb[1],hb[2],hb[3]);
      *(ushort4*)(woth+orow+4)  = make_ushort4(hb[4],hb[5],hb[6],hb[7]);
      *(ushort4*)(woth+orow+8)  = make_ushort4(hb[8],hb[9],hb[10],hb[11]);
      *(ushort4*)(woth+orow+12) = make_ushort4(hb[12],hb[13],hb[14],hb[15]);
    }
    return;
  }
  if(bx < 3136){
    float (*L)[68] = (float(*)[68])SL;
    int k0 = (bx - 3072)*64;
    int rr = t>>2, cg = t&3;
    const float* src = Wc + (size_t)(k0+rr)*64 + cg*16;
    float4 a = *(const float4*)(src);
    float4 b = *(const float4*)(src+4);
    float4 c = *(const float4*)(src+8);
    float4 d = *(const float4*)(src+12);
    *(float4*)&L[rr][cg*16+0]  = a;
    *(float4*)&L[rr][cg*16+4]  = b;
    *(float4*)&L[rr][cg*16+8]  = c;
    *(float4*)&L[rr][cg*16+12] = d;
    __syncthreads();
    int nr = t>>2, kg = t&3;
    unsigned short hb[16], lb[16];
#pragma unroll
    for(int j=0;j<16;j++){
      float v = L[kg*16+j][nr];
      bsplit(v, hb[j], lb[j]);
    }
    size_t orow = (size_t)nr*4096 + k0 + kg*16;
    *(ushort4*)(wcth+orow+0)  = make_ushort4(hb[0],hb[1],hb[2],hb[3]);
    *(ushort4*)(wcth+orow+4)  = make_ushort4(hb[4],hb[5],hb[6],hb[7]);
    *(ushort4*)(wcth+orow+8)  = make_ushort4(hb[8],hb[9],hb[10],hb[11]);
    *(ushort4*)(wcth+orow+12) = make_ushort4(hb[12],hb[13],hb[14],hb[15]);
    *(ushort4*)(wctl+orow+0)  = make_ushort4(lb[0],lb[1],lb[2],lb[3]);
    *(ushort4*)(wctl+orow+4)  = make_ushort4(lb[4],lb[5],lb[6],lb[7]);
    *(ushort4*)(wctl+orow+8)  = make_ushort4(lb[8],lb[9],lb[10],lb[11]);
    *(ushort4*)(wctl+orow+12) = make_ushort4(lb[12],lb[13],lb[14],lb[15]);
    return;
  }
  {
    float* row = SL;
    float (*red)[64] = (float(*)[64])(SL + 1024);
    int tr = bx - 3136;
    *(float4*)(row + t*4) = *(const float4*)(hs + (size_t)tr*HIDDEN + t*4);
    __syncthreads();
    int n = t & 63, part = t>>6;
    float s = 0.f;
    if(n < 48){
      const float* w = Wg + n;
      for(int kx = part*256; kx < part*256+256; kx++)
        s += row[kx]*w[(size_t)kx*48];
    }
    red[part][n] = s;
    __syncthreads();
    if(part==0 && n<48){
      float x = red[0][n]+red[1][n]+red[2][n]+red[3][n] + bg[n];
      gatep[(size_t)tr*48 + n] = 1.f/(1.f+expf(-x));
    }
  }
}

// ---------------- QKV MFMA GEMM: 128x64 tiles, grid(48,16); LROW=40 (reads 2-way=free); fused vth ----------------
#define LROW 40
__global__ __launch_bounds__(256) void mfma_qkv_k(
    const unsigned short* __restrict__ ahg, const unsigned short* __restrict__ alg,
    const unsigned short* __restrict__ bhg, const unsigned short* __restrict__ blg,
    unsigned short* __restrict__ qbh, unsigned short* __restrict__ qbl,
    unsigned short* __restrict__ kbh, unsigned short* __restrict__ kbl,
    unsigned short* __restrict__ vbh, unsigned short* __restrict__ vth)
{
  __shared__ unsigned short SH[15360];  // SA 5120 | SAl 5120 | SB 2560 | SBl 2560
  unsigned short* SA  = SH;
  unsigned short* SAl = SH + 5120;
  unsigned short* SB  = SH + 10240;
  unsigned short* SBl = SH + 12800;
  int tid = threadIdx.x;
  int bn = blockIdx.x*64, bm = blockIdx.y*128;
  bool tp = (blockIdx.x < 32);       // Q,K columns: 3-pass split
  int sr = tid>>2, skg = (tid&3)*8;
  const unsigned short* gA  = ahg + (size_t)(bm+sr)*HIDDEN + skg;
  const unsigned short* gAl = alg + (size_t)(bm+sr)*HIDDEN + skg;
  const unsigned short* gB  = bhg + (size_t)(bn+sr)*HIDDEN + skg;
  const unsigned short* gBl = blg + (size_t)(bn+sr)*HIDDEN + skg;
  int wlds = sr*LROW + skg;
  int wv = tid>>6, ln = tid&63;
  int wm = (wv&1)*64, wn = (wv>>1)*32;
  int fr = ln&15, fq = ln>>4;
  f4v acc[4][2] = {};
  for(int k0=0;k0<HIDDEN;k0+=32){
    s8v a0 = *(const s8v*)(gA + k0);
    s8v a1 = *(const s8v*)(gA + 65536 + k0);     // +64 rows
    s8v b0 = *(const s8v*)(gB + k0);
    s8v a0l, a1l, b0l;
    if(tp){
      a0l = *(const s8v*)(gAl + k0);
      a1l = *(const s8v*)(gAl + 65536 + k0);
      b0l = *(const s8v*)(gBl + k0);
    }
    __syncthreads();
    *(s8v*)&SA[wlds] = a0; *(s8v*)&SA[wlds + 64*LROW] = a1;
    *(s8v*)&SB[wlds] = b0;
    if(tp){
      *(s8v*)&SAl[wlds] = a0l; *(s8v*)&SAl[wlds + 64*LROW] = a1l;
      *(s8v*)&SBl[wlds] = b0l;
    }
    __syncthreads();
    s8v af[4], bf[2], tf;
#pragma unroll
    for(int i=0;i<4;i++) af[i] = *(const s8v*)&SA[(wm+i*16+fr)*LROW + fq*8];
#pragma unroll
    for(int j=0;j<2;j++) bf[j] = *(const s8v*)&SB[(wn+j*16+fr)*LROW + fq*8];
#pragma unroll
    for(int i=0;i<4;i++)
#pragma unroll
      for(int j=0;j<2;j++)
        acc[i][j] = __builtin_amdgcn_mfma_f32_16x16x32_bf16(af[i], bf[j], acc[i][j], 0,0,0);
    if(tp){
#pragma unroll
      for(int i=0;i<4;i++){
        tf = *(const s8v*)&SAl[(wm+i*16+fr)*LROW + fq*8];
#pragma unroll
        for(int j=0;j<2;j++)
          acc[i][j] = __builtin_amdgcn_mfma_f32_16x16x32_bf16(tf, bf[j], acc[i][j], 0,0,0);
      }
#pragma unroll
      for(int j=0;j<2;j++){
        tf = *(const s8v*)&SBl[(wn+j*16+fr)*LROW + fq*8];
#pragma unroll
        for(int i=0;i<4;i++)
          acc[i][j] = __builtin_amdgcn_mfma_f32_16x16x32_bf16(af[i], tf, acc[i][j], 0,0,0);
      }
    }
  }
  // epilogue: LDS-stage bf16 [t_loc][d] (stride 72: 2-way = free) then coalesced 16B stores
  int z = bn >> 10;
  int head = (bn & 1023) >> 6;
  unsigned short* Cs = SH;          // 128*72 = 9216 shorts <= 15360
  unsigned short* dsth = (z==0)?qbh:((z==1)?kbh:vbh);
  size_t obase = ((size_t)head*TT + bm)*HD;
  __syncthreads();
#pragma unroll
  for(int i=0;i<4;i++)
#pragma unroll
    for(int j=0;j<2;j++)
#pragma unroll
      for(int r=0;r<4;r++)
        Cs[(wm+i*16+fq*4+r)*72 + wn+j*16+fr] = f2bf(acc[i][j][r]);
  __syncthreads();
#pragma unroll
  for(int u=0;u<4;u++){
    int c = u*256 + tid;
    *(s8v*)(dsth + obase + c*8) = *(const s8v*)&Cs[(c>>3)*72 + (c&7)*8];
  }
  if(z<2){
    unsigned short* dstl = (z==0)?qbl:kbl;
    __syncthreads();
#pragma unroll
    for(int i=0;i<4;i++)
#pragma unroll
      for(int j=0;j<2;j++)
#pragma unroll
        for(int r=0;r<4;r++){
          float v = acc[i][j][r];
          Cs[(wm+i*16+fq*4+r)*72 + wn+j*16+fr] = f2bf(v - bf2f(f2bf(v)));
        }
    __syncthreads();
#pragma unroll
    for(int u=0;u<4;u++){
      int c = u*256 + tid;
      *(s8v*)(dstl + obase + c*8) = *(const s8v*)&Cs[(c>>3)*72 + (c&7)*8];
    }
  }else{
    // fused conv_vt: Cs holds V hi tile [t_loc][d] -> write v^T [h][d][t]
    int d = tid>>2, tg = (tid&3)*32;
    s8v r0,r1,r2,r3;
#pragma unroll
    for(int u=0;u<8;u++){
      r0[u] = (short)Cs[(tg+u)*72 + d];
      r1[u] = (short)Cs[(tg+8+u)*72 + d];
      r2[u] = (short)Cs[(tg+16+u)*72 + d];
      r3[u] = (short)Cs[(tg+24+u)*72 + d];
    }
    unsigned short* dv = vth + ((size_t)head*HD + d)*TT + bm + tg;
    *(s8v*)(dv)    = r0;
    *(s8v*)(dv+8)  = r1;
    *(s8v*)(dv+16) = r2;
    *(s8v*)(dv+24) = r3;
  }
}

// ---------------- compress MFMA GEMM: [kblk;vblk](1024x4096) @ WcT, split-K ----------------
#define CROW 40
__global__ __launch_bounds__(256) void mfma_compress_k(
    const unsigned short* __restrict__ kbh, const unsigned short* __restrict__ kbl,
    const unsigned short* __restrict__ vbh,
    const unsigned short* __restrict__ wcth, const unsigned short* __restrict__ wctl,
    float* __restrict__ ccpart)
{
  __shared__ unsigned short As[64*CROW], Al[64*CROW], Bs[64*CROW], Bl[64*CROW];
  int chunk = blockIdx.x;
  int mt = blockIdx.y;
  bool isK = (mt < 8);
  const unsigned short* Ag  = isK ? (kbh + (size_t)mt*262144) : (vbh + (size_t)(mt-8)*262144);
  const unsigned short* Agl = kbl + (size_t)(isK ? mt : 0)*262144;
  int tid = threadIdx.x;
  int sr = tid>>2, skg = (tid&3)*8;
  int k0b = chunk*512;
  const unsigned short* gA  = Ag  + (size_t)sr*4096 + k0b + skg;
  const unsigned short* gAl = Agl + (size_t)sr*4096 + k0b + skg;
  const unsigned short* gB  = wcth + (size_t)sr*4096 + k0b + skg;
  const unsigned short* gBl = wctl + (size_t)sr*4096 + k0b + skg;
  int wv = tid>>6, ln = tid&63;
  int fr = ln&15, fq = ln>>4;
  int wlds = sr*CROW + skg;
  f4v acc[4] = {};
  for(int ks=0; ks<512; ks+=32){
    s8v a0 = *(const s8v*)(gA + ks);
    s8v b0 = *(const s8v*)(gB + ks);
    s8v b1 = *(const s8v*)(gBl + ks);
    s8v a1 = {};
    if(isK) a1 = *(const s8v*)(gAl + ks);
    __syncthreads();
    *(s8v*)&As[wlds] = a0;
    *(s8v*)&Bs[wlds] = b0;
    *(s8v*)&Bl[wlds] = b1;
    if(isK) *(s8v*)&Al[wlds] = a1;
    __syncthreads();
    s8v bfh = *(const s8v*)&Bs[(wv*16+fr)*CROW + fq*8];
    s8v bfl = *(const s8v*)&Bl[(wv*16+fr)*CROW + fq*8];
#pragma unroll
    for(int m=0;m<4;m++){
      s8v af = *(const s8v*)&As[(m*16+fr)*CROW + fq*8];
      acc[m] = __builtin_amdgcn_mfma_f32_16x16x32_bf16(af, bfh, acc[m], 0,0,0);
      acc[m] = __builtin_amdgcn_mfma_f32_16x16x32_bf16(af, bfl, acc[m], 0,0,0);
      if(isK){
        s8v afl = *(const s8v*)&Al[(m*16+fr)*CROW + fq*8];
        acc[m] = __builtin_amdgcn_mfma_f32_16x16x32_bf16(afl, bfh, acc[m], 0,0,0);
      }
    }
  }
  float* dst = ccpart + ((size_t)chunk*1024 + mt*64)*64;
#pragma unroll
  for(int m=0;m<4;m++)
#pragma unroll
    for(int r=0;r<4;r++)
      dst[(size_t)(m*16+fq*4+r)*64 + wv*16 + fr] = acc[m][r];
}

// ---------------- reduce partials + bias + gelu -> kc split bf16, vc^T bf16 ----------------
__global__ __launch_bounds__(256) void compress_fin(
    const float* __restrict__ ccpart, const float* __restrict__ bcp,
    unsigned short* __restrict__ kch, unsigned short* __restrict__ kcl,
    unsigned short* __restrict__ vcth)
{
  int idx = blockIdx.x*256 + threadIdx.x;   // 65536
  int row = idx>>6, col = idx&63;
  float s = 0.f;
#pragma unroll
  for(int c=0;c<8;c++) s += ccpart[(size_t)c*65536 + idx];
  s += bcp[col];
  float g = 0.5f*s*(1.f+erff(s*0.70710678118654752f));
  if(row < 512){
    unsigned short hi = f2bf(g);
    kch[idx] = hi;
    kcl[idx] = f2bf(g - bf2f(hi));
  }else{
    int r = row - 512;
    int h = r>>5, j = r&31;
    vcth[((size_t)h*64 + col)*32 + j] = f2bf(g);
  }
}

// ---------------- compressed attention + block stats + top-k + avg_k (fused) ----------------
__global__ __launch_bounds__(256) void comp_attn_mfma(
    const unsigned short* __restrict__ qbh, const unsigned short* __restrict__ qbl,
    const unsigned short* __restrict__ kch, const unsigned short* __restrict__ kcl,
    const unsigned short* __restrict__ vcth,
    const float* __restrict__ ksc, const float* __restrict__ kbi,
    float* __restrict__ comp, unsigned* __restrict__ maskb,
    float* __restrict__ out_avgk, float* __restrict__ out_kratio, float* __restrict__ out_nent)
{
  __shared__ unsigned short Pl[4*16*40];
  __shared__ float colsum[4][32];
  int tid = threadIdx.x;
  int wave = __builtin_amdgcn_readfirstlane(tid>>6);
  int ln = tid&63;
  int fr = ln&15, fq = ln>>4;
  int i = blockIdx.x, h = blockIdx.y;

  const unsigned short* qrh = qbh + ((size_t)h*TT + i*64 + wave*16 + fr)*HD + fq*8;
  const unsigned short* qrl = qbl + ((size_t)h*TT + i*64 + wave*16 + fr)*HD + fq*8;
  s8v bh0 = *(const s8v*)(qrh);
  s8v bh1 = *(const s8v*)(qrh + 32);
  s8v bl0 = *(const s8v*)(qrl);
  s8v bl1 = *(const s8v*)(qrl + 32);

  f4v sv[2] = {};
#pragma unroll
  for(int mt=0;mt<2;mt++){
    const unsigned short* ar = kch + ((size_t)h*32 + mt*16 + fr)*HD + fq*8;
    const unsigned short* al = kcl + ((size_t)h*32 + mt*16 + fr)*HD + fq*8;
    s8v ah0 = *(const s8v*)(ar);
    s8v ah1 = *(const s8v*)(ar + 32);
    s8v al0 = *(const s8v*)(al);
    s8v al1 = *(const s8v*)(al + 32);
    sv[mt] = __builtin_amdgcn_mfma_f32_16x16x32_bf16(ah0, bh0, sv[mt], 0,0,0);
    sv[mt] = __builtin_amdgcn_mfma_f32_16x16x32_bf16(ah1, bh1, sv[mt], 0,0,0);
    sv[mt] = __builtin_amdgcn_mfma_f32_16x16x32_bf16(al0, bh0, sv[mt], 0,0,0);
    sv[mt] = __builtin_amdgcn_mfma_f32_16x16x32_bf16(al1, bh1, sv[mt], 0,0,0);
    sv[mt] = __builtin_amdgcn_mfma_f32_16x16x32_bf16(ah0, bl0, sv[mt], 0,0,0);
    sv[mt] = __builtin_amdgcn_mfma_f32_16x16x32_bf16(ah1, bl1, sv[mt], 0,0,0);
  }
#pragma unroll
  for(int mt=0;mt<2;mt++)
#pragma unroll
    for(int r=0;r<4;r++) sv[mt][r] *= 0.125f;

  // ---- block-stats reduction: column sums over the 64 queries of this block ----
  float cs[8];
#pragma unroll
  for(int mt=0;mt<2;mt++)
#pragma unroll
    for(int r=0;r<4;r++) cs[mt*4+r] = sv[mt][r];
#pragma unroll
  for(int o=1;o<16;o<<=1)
#pragma unroll
    for(int u=0;u<8;u++) cs[u] += __shfl_xor(cs[u], o, 64);
  if(fr==0){
#pragma unroll
    for(int mt=0;mt<2;mt++)
#pragma unroll
      for(int r=0;r<4;r++) colsum[wave][mt*16 + fq*4 + r] = cs[mt*4+r];
  }
  __syncthreads();
  if(wave==0 && ln<32){
    int j = ln;
    float bs = (colsum[0][j]+colsum[1][j]+colsum[2][j]+colsum[3][j]) * (1.f/64.f);
    float m = rmax32(bs);
    float e = expf(bs - m);
    float se = rsum32(e);
    float prob = e/se;
    float ent = rsum32(-prob * logf(prob + 1e-9f));
    float nent = ent / (3.4657359027997265f + 1e-9f);   // log(32)
    float kl = ksc[h]*nent + kbi[h];
    float kr = 1.f/(1.f + expf(-kl));
    float dkfl = fminf(fmaxf(8.f*kr, 1.f), 8.f);
    int dk = (int)dkfl;
    unsigned sel = 0u;
    for(int r=0;r<dk;r++){
      bool unpicked = ((sel>>j)&1u)==0u;
      float cand = unpicked ? bs : -3.4e38f;
      float mx = rmax32(cand);
      unsigned long long b = __ballot(cand == mx);
      int idxsel = __ffsll(b & 0xffffffffull) - 1;
      sel |= (1u<<idxsel);
    }
    sel |= (1u<<i);
    if(j==0){
      int hb = h*32 + i;
      maskb[hb] = sel;
      out_kratio[hb] = kr;
      out_nent[hb] = nent;
      atomicAdd(out_avgk, (float)dk * (1.f/512.f));   // exact: multiples of 2^-9
    }
  }

  // ---- softmax + PV ----
  float mx = -3.4e38f;
#pragma unroll
  for(int mt=0;mt<2;mt++)
#pragma unroll
    for(int r=0;r<4;r++) mx = fmaxf(mx, sv[mt][r]);
  mx = fmaxf(mx, __shfl_xor(mx,16,64));
  mx = fmaxf(mx, __shfl_xor(mx,32,64));
  unsigned short* Pw = Pl + wave*16*40;
  float es = 0.f;
#pragma unroll
  for(int mt=0;mt<2;mt++)
#pragma unroll
    for(int r=0;r<4;r++){
      float p = __expf(sv[mt][r] - mx);
      es += p;
      Pw[fr*40 + mt*16 + fq*4 + r] = f2bf(p);
    }
  es += __shfl_xor(es,16,64);
  es += __shfl_xor(es,32,64);

  s8v ap = *(const s8v*)&Pw[fr*40 + fq*8];
  f4v acc[4] = {};
#pragma unroll
  for(int nt=0;nt<4;nt++){
    s8v bv = *(const s8v*)(vcth + ((size_t)h*64 + nt*16 + fr)*32 + fq*8);
    acc[nt] = __builtin_amdgcn_mfma_f32_16x16x32_bf16(ap, bv, acc[nt], 0,0,0);
  }
  float lv[4];
#pragma unroll
  for(int r=0;r<4;r++) lv[r] = __shfl(es, fq*4+r, 64);
#pragma unroll
  for(int nt=0;nt<4;nt++)
#pragma unroll
    for(int r=0;r<4;r++){
      int tq = i*64 + wave*16 + fq*4 + r;
      comp[((size_t)h*TT + tq)*HD + nt*16 + fr] = acc[nt][r]/lv[r];
    }
}

// ---------------- fused sliding-window + fine attention + gated combine ----------------
__global__ __launch_bounds__(256) void attn_fused(
    const unsigned short* __restrict__ qbh, const unsigned short* __restrict__ kbh,
    const unsigned short* __restrict__ vth, const unsigned* __restrict__ maskb,
    const float* __restrict__ comp, const float* __restrict__ gatep,
    unsigned short* __restrict__ mergedh)
{
  __shared__ unsigned short Kb[64*72];
  __shared__ unsigned short Vt[64*72];
  __shared__ unsigned short Pf[4*16*72];
  __shared__ unsigned short Ps[4*16*72];
  int tid = threadIdx.x;
  int wave = __builtin_amdgcn_readfirstlane(tid>>6);
  int ln = tid & 63;
  int fr = ln & 15, fq = ln >> 4;
  int hb = blockIdx.x; int h = hb>>5, i = hb&31;
  unsigned mb_s = (1u<<i) | (i ? (1u<<(i-1)) : 0u);
  unsigned mb_f = maskb[hb];
  unsigned mb = mb_s | mb_f;

  const unsigned short* qrow = qbh + ((size_t)h*TT + i*64 + wave*16 + fr)*HD + fq*8;
  s8v bq0 = *(const s8v*)(qrow);
  s8v bq1 = *(const s8v*)(qrow + 32);

  f4v acc_f[4] = {}, acc_s[4] = {};
  float mf = -3.4e38f, lf = 0.f, ms = -3.4e38f, ls = 0.f;

  int srow = tid>>2, sg = (tid&3)*16;
  unsigned short* Pfw = Pf + wave*16*72;
  unsigned short* Psw = Ps + wave*16*72;
  int qpos = wave*16 + fr;

  for(int j=0;j<NB;j++){
    if(!((mb>>j)&1u)) continue;
    __syncthreads();
    {
      const unsigned short* ks_ = kbh + ((size_t)h*TT + j*64 + srow)*HD + sg;
      *(s8v*)&Kb[srow*72 + sg]     = *(const s8v*)(ks_);
      *(s8v*)&Kb[srow*72 + sg + 8] = *(const s8v*)(ks_ + 8);
      const unsigned short* vs_ = vth + ((size_t)h*HD + srow)*TT + j*64 + sg;
      *(s8v*)&Vt[srow*72 + sg]     = *(const s8v*)(vs_);
      *(s8v*)&Vt[srow*72 + sg + 8] = *(const s8v*)(vs_ + 8);
    }
    __syncthreads();

    f4v sv[4] = {};
#pragma unroll
    for(int mt=0;mt<4;mt++){
      s8v ak0 = *(const s8v*)&Kb[(mt*16+fr)*72 + fq*8];
      s8v ak1 = *(const s8v*)&Kb[(mt*16+fr)*72 + fq*8 + 32];
      sv[mt] = __builtin_amdgcn_mfma_f32_16x16x32_bf16(ak0, bq0, sv[mt], 0,0,0);
      sv[mt] = __builtin_amdgcn_mfma_f32_16x16x32_bf16(ak1, bq1, sv[mt], 0,0,0);
    }
#pragma unroll
    for(int mt=0;mt<4;mt++)
#pragma unroll
      for(int r=0;r<4;r++) sv[mt][r] *= 0.125f;

    bool in_f = ((mb_f>>j)&1u) != 0u;
    bool in_s = (j==i) || (j+1==i);

    if(in_f){
      float mx = -3.4e38f;
#pragma unroll
      for(int mt=0;mt<4;mt++)
#pragma unroll
        for(int r=0;r<4;r++) mx = fmaxf(mx, sv[mt][r]);
      mx = fmaxf(mx, __shfl_xor(mx,16,64));
      mx = fmaxf(mx, __shfl_xor(mx,32,64));
      float mnew = fmaxf(mf, mx);
      float es = 0.f;
#pragma unroll
      for(int mt=0;mt<4;mt++)
#pragma unroll
        for(int r=0;r<4;r++){
          float p = __expf(sv[mt][r] - mnew);
          es += p;
          Pfw[fr*72 + mt*16 + fq*4 + r] = f2bf(p);
        }
      es += __shfl_xor(es,16,64);
      es += __shfl_xor(es,32,64);
      float alpha = __expf(mf - mnew);
      lf = lf*alpha + es;
      mf = mnew;
      float av[4];
#pragma unroll
      for(int r=0;r<4;r++) av[r] = __shfl(alpha, fq*4+r, 64);
#pragma unroll
      for(int nt=0;nt<4;nt++)
#pragma unroll
        for(int r=0;r<4;r++) acc_f[nt][r] *= av[r];
    }
    if(in_s){
      if(j==i){
#pragma unroll
        for(int mt=0;mt<4;mt++)
#pragma unroll
          for(int r=0;r<4;r++)
            if((mt*16 + fq*4 + r) > qpos) sv[mt][r] = -3.4e38f;
      }
      float mx = -3.4e38f;
#pragma unroll
      for(int mt=0;mt<4;mt++)
#pragma unroll
        for(int r=0;r<4;r++) mx = fmaxf(mx, sv[mt][r]);
      mx = fmaxf(mx, __shfl_xor(mx,16,64));
      mx = fmaxf(mx, __shfl_xor(mx,32,64));
      float mnew = fmaxf(ms, mx);
      float es = 0.f;
#pragma unroll
      for(int mt=0;mt<4;mt++)
#pragma unroll
        for(int r=0;r<4;r++){
          float p = __expf(sv[mt][r] - mnew);
          es += p;
          Psw[fr*72 + mt*16 + fq*4 + r] = f2bf(p);
        }
      es += __shfl_xor(es,16,64);
      es += __shfl_xor(es,32,64);
      float alpha = __expf(ms - mnew);
      ls = ls*alpha + es;
      ms = mnew;
      float av[4];
#pragma unroll
      for(int r=0;r<4;r++) av[r] = __shfl(alpha, fq*4+r, 64);
#pragma unroll
      for(int nt=0;nt<4;nt++)
#pragma unroll
        for(int r=0;r<4;r++) acc_s[nt][r] *= av[r];
    }

    if(in_f){
      s8v ap0 = *(const s8v*)&Pfw[fr*72 + fq*8];
      s8v ap1 = *(const s8v*)&Pfw[fr*72 + fq*8 + 32];
#pragma unroll
      for(int nt=0;nt<4;nt++){
        s8v bv0 = *(const s8v*)&Vt[(nt*16+fr)*72 + fq*8];
        s8v bv1 = *(const s8v*)&Vt[(nt*16+fr)*72 + fq*8 + 32];
        acc_f[nt] = __builtin_amdgcn_mfma_f32_16x16x32_bf16(ap0, bv0, acc_f[nt], 0,0,0);
        acc_f[nt] = __builtin_amdgcn_mfma_f32_16x16x32_bf16(ap1, bv1, acc_f[nt], 0,0,0);
      }
    }
    if(in_s){
      s8v ap0 = *(const s8v*)&Psw[fr*72 + fq*8];
      s8v ap1 = *(const s8v*)&Psw[fr*72 + fq*8 + 32];
#pragma unroll
      for(int nt=0;nt<4;nt++){
        s8v bv0 = *(const s8v*)&Vt[(nt*16+fr)*72 + fq*8];
        s8v bv1 = *(const s8v*)&Vt[(nt*16+fr)*72 + fq*8 + 32];
        acc_s[nt] = __builtin_amdgcn_mfma_f32_16x16x32_bf16(ap0, bv0, acc_s[nt], 0,0,0);
        acc_s[nt] = __builtin_amdgcn_mfma_f32_16x16x32_bf16(ap1, bv1, acc_s[nt], 0,0,0);
      }
    }
  }

  float lvf[4], lvs[4], g0[4], g1[4], g2[4];
#pragma unroll
  for(int r=0;r<4;r++){
    lvf[r] = __shfl(lf, fq*4+r, 64);
    lvs[r] = __shfl(ls, fq*4+r, 64);
    int t = i*64 + wave*16 + fq*4 + r;
    const float* g = gatep + (size_t)t*48 + h*3;
    g0[r] = g[0]; g1[r] = g[1]; g2[r] = g[2];
  }
#pragma unroll
  for(int nt=0;nt<4;nt++){
#pragma unroll
    for(int r=0;r<4;r++){
      int t = i*64 + wave*16 + fq*4 + r;
      int d = nt*16 + fr;
      float of = acc_f[nt][r] / lvf[r];
      float os = acc_s[nt][r] / lvs[r];
      float cp = comp[((size_t)h*TT + t)*HD + d];
      mergedh[(size_t)t*1024 + h*64 + d] = f2bf(g0[r]*os + g1[r]*cp + g2[r]*of);
    }
  }
}

// ---------------- output projection MFMA GEMM: 128x64 tiles, grid(16,16) ----------------
__global__ __launch_bounds__(256) void mfma_proj_k(
    const unsigned short* __restrict__ ahg, const unsigned short* __restrict__ bhg,
    float* __restrict__ C)
{
  __shared__ unsigned short SA[128*LROW], SB[64*LROW];
  int tid = threadIdx.x;
  int bn = blockIdx.x*64, bm = blockIdx.y*128;
  int sr = tid>>2, skg = (tid&3)*8;
  const unsigned short* gA = ahg + (size_t)(bm+sr)*HIDDEN + skg;
  const unsigned short* gB = bhg + (size_t)(bn+sr)*HIDDEN + skg;
  int wlds = sr*LROW + skg;
  int wv = tid>>6, ln = tid&63;
  int wm = (wv&1)*64, wn = (wv>>1)*32;
  int fr = ln&15, fq = ln>>4;
  f4v acc[4][2] = {};
  for(int k0=0;k0<HIDDEN;k0+=32){
    s8v a0 = *(const s8v*)(gA + k0);
    s8v a1 = *(const s8v*)(gA + 65536 + k0);
    s8v b0 = *(const s8v*)(gB + k0);
    __syncthreads();
    *(s8v*)&SA[wlds] = a0; *(s8v*)&SA[wlds + 64*LROW] = a1;
    *(s8v*)&SB[wlds] = b0;
    __syncthreads();
    s8v af[4], bf[2];
#pragma unroll
    for(int i=0;i<4;i++) af[i] = *(const s8v*)&SA[(wm+i*16+fr)*LROW + fq*8];
#pragma unroll
    for(int j=0;j<2;j++) bf[j] = *(const s8v*)&SB[(wn+j*16+fr)*LROW + fq*8];
#pragma unroll
    for(int i=0;i<4;i++)
#pragma unroll
      for(int j=0;j<2;j++)
        acc[i][j] = __builtin_amdgcn_mfma_f32_16x16x32_bf16(af[i], bf[j], acc[i][j], 0,0,0);
  }
#pragma unroll
  for(int i=0;i<4;i++){
    int mb = bm + wm + i*16 + fq*4;
#pragma unroll
    for(int j=0;j<2;j++){
      int n = bn + wn + j*16 + fr;
      float* dst = C + (size_t)mb*HIDDEN + n;
#pragma unroll
      for(int r=0;r<4;r++) dst[(size_t)r*HIDDEN] = acc[i][j][r];
    }
  }
}

extern "C" void kernel_launch(void* const* d_in, const int* in_sizes, int n_in,
                              void* d_out, int out_size, void* d_ws, size_t ws_size,
                              hipStream_t stream) {
  (void)in_sizes; (void)n_in; (void)out_size; (void)ws_size;
  const float* hs  = (const float*)d_in[0];
  const float* Wq  = (const float*)d_in[1];
  const float* Wk  = (const float*)d_in[2];
  const float* Wv  = (const float*)d_in[3];
  const float* Wo  = (const float*)d_in[4];
  const float* Wc  = (const float*)d_in[5];
  const float* bcp = (const float*)d_in[6];
  const float* ksc = (const float*)d_in[7];
  const float* kbi = (const float*)d_in[8];
  const float* Wg  = (const float*)d_in[9];
  const float* bg  = (const float*)d_in[10];
  float* out = (float*)d_out;

  float* ws = (float*)d_ws;
  float* gatep  = ws;                         // 98304
  unsigned short* kch  = (unsigned short*)(gatep + 98304);   // 32768 shorts
  unsigned short* kcl  = kch + 32768;
  unsigned short* vcth = kcl + 32768;
  float* comp   = gatep + 98304 + 65536;      // 2097152 (hsh/hsl alias)
  float* wthf   = comp + 2097152;             // 1572864 (wth region)
  float* wtlf   = wthf + 1572864;             // 1572864 (wtl region)
  unsigned short* mergedh = (unsigned short*)(wtlf + 1572864);  // 1048576 floats
  unsigned* maskb = (unsigned*)(wtlf + 1572864 + 1048576);      // 512
  unsigned short* woth = (unsigned short*)(wtlf + 1572864 + 1048576 + 512);   // 524288 f
  unsigned short* qbh  = woth + 1048576;      // each 2097152 shorts:
  unsigned short* qbl  = qbh + 2097152;
  unsigned short* kbh  = qbl + 2097152;
  unsigned short* kbl  = kbh + 2097152;
  unsigned short* vbh  = kbl + 2097152;
  unsigned short* vth  = vbh + 2097152;
  unsigned short* wcth = vth + 2097152;       // 262144 shorts
  unsigned short* wctl = wcth + 262144;
  float* ccpart = (float*)(wctl + 262144);    // 524288 f

  unsigned short* hsh = (unsigned short*)comp;
  unsigned short* hsl = (unsigned short*)(comp + 1048576);
  unsigned short* wth = (unsigned short*)wthf;
  unsigned short* wtl = (unsigned short*)wtlf;

  float* out_avgk   = out + 2097152;
  float* out_kratio = out + 2097153;
  float* out_nent   = out + 2097665;

  prep_all<<<dim3(5184), 256, 0, stream>>>(hs, Wq, Wk, Wv, Wo, Wc, Wg, bg,
                                           hsh, hsl, wth, wtl, woth, wcth, wctl,
                                           gatep, out_avgk);
  mfma_qkv_k<<<dim3(48,16), 256, 0, stream>>>(hsh, hsl, wth, wtl,
                                              qbh, qbl, kbh, kbl, vbh, vth);
  mfma_compress_k<<<dim3(8,16), 256, 0, stream>>>(kbh, kbl, vbh, wcth, wctl, ccpart);
  compress_fin<<<dim3(256), 256, 0, stream>>>(ccpart, bcp, kch, kcl, vcth);
  comp_attn_mfma<<<dim3(32,16), 256, 0, stream>>>(qbh, qbl, kch, kcl, vcth,
                                                  ksc, kbi, comp, maskb,
                                                  out_avgk, out_kratio, out_nent);
  attn_fused<<<dim3(512), 256, 0, stream>>>(qbh, kbh, vth, maskb, comp, gatep, mergedh);
  mfma_proj_k<<<dim3(16,16), 256, 0, stream>>>(mergedh, woth, out);
}